// Round 1
// baseline (657.142 us; speedup 1.0000x reference)
//
#include <hip/hip_runtime.h>

// Problem constants (from reference): B=4, S=2048 -> M=8192 rows; OUT_F=N=4096; IN_F=K=4096; GROUP=128.
#define K_DIM 4096
#define N_DIM 4096
#define M_DIM 8192

typedef __bf16 bf16;
typedef __attribute__((ext_vector_type(8))) __bf16 bf16x8;
typedef __attribute__((ext_vector_type(4))) float f32x4;
typedef __attribute__((ext_vector_type(8))) unsigned short u16x8;

// fp32 -> bf16 round-to-nearest-even (bit trick; inputs are normal finite values)
__device__ inline unsigned short f2bf(float f) {
    unsigned u = __builtin_bit_cast(unsigned, f);
    u += 0x7fffu + ((u >> 16) & 1u);
    return (unsigned short)(u >> 16);
}

// ---- prep 1: x fp32 -> bf16 (each thread converts 8 elements) ----
__global__ __launch_bounds__(256) void cvt_x_kernel(const float* __restrict__ x,
                                                    unsigned short* __restrict__ o) {
    const size_t i = (size_t)blockIdx.x * 256 + threadIdx.x;
    const float4* p = (const float4*)x + i * 2;
    float4 a = p[0], b = p[1];
    u16x8 v;
    v[0] = f2bf(a.x); v[1] = f2bf(a.y); v[2] = f2bf(a.z); v[3] = f2bf(a.w);
    v[4] = f2bf(b.x); v[5] = f2bf(b.y); v[6] = f2bf(b.z); v[7] = f2bf(b.w);
    *((u16x8*)o + i) = v;
}

// ---- prep 2: W[n,k] = bf16(sign_w[n,k] * scales[(n*K + k)/128]) ----
// Thread i handles flat elements i*8 .. i*8+7 -> all in scale group i/16.
__global__ __launch_bounds__(256) void wprep_kernel(const float* __restrict__ sw,
                                                    const float* __restrict__ scales,
                                                    unsigned short* __restrict__ o) {
    const size_t i = (size_t)blockIdx.x * 256 + threadIdx.x;
    const float s = scales[i >> 4];
    const float4* p = (const float4*)sw + i * 2;
    float4 a = p[0], b = p[1];
    u16x8 v;
    v[0] = f2bf(a.x * s); v[1] = f2bf(a.y * s); v[2] = f2bf(a.z * s); v[3] = f2bf(a.w * s);
    v[4] = f2bf(b.x * s); v[5] = f2bf(b.y * s); v[6] = f2bf(b.z * s); v[7] = f2bf(b.w * s);
    *((u16x8*)o + i) = v;
}

__device__ inline void gll16(const bf16* g, bf16* l) {
    __builtin_amdgcn_global_load_lds(
        (const __attribute__((address_space(1))) void*)g,
        (__attribute__((address_space(3))) void*)l, 16, 0, 0);
}

// ---- GEMM: C[m,n] = sum_k A[m,k] * W[n,k]; A:(M,K) bf16, W:(N,K) bf16, C fp32 ----
// m97 structure: 128x128 tile, BK=32, 256 threads = 2x2 waves, each wave 4x4 of 16x16x32 MFMA.
__global__ __launch_bounds__(256) void gemm_bt_kernel(const bf16* __restrict__ A,
                                                      const bf16* __restrict__ W,
                                                      float* __restrict__ C) {
    __shared__ bf16 As[128 * 32];  // 8 KB, row-major [row][k], NO padding (global_load_lds)
    __shared__ bf16 Bs[128 * 32];  // 8 KB

    const int t = threadIdx.x;
    const int m0 = blockIdx.y * 128;
    const int n0 = blockIdx.x * 128;
    const int lane = t & 63;
    const int w = t >> 6;
    const int wm = (w >> 1) * 64;   // wave's m-offset within tile
    const int wn = (w & 1) * 64;    // wave's n-offset within tile
    const int lr = lane & 15;       // row within 16x16 fragment
    const int lq = lane >> 4;       // quad

    f32x4 acc[4][4] = {};

    // Staging: 128 rows x 32 cols bf16 = 512 16B segments per tile; thread t does segs t and t+256.
    const bf16* ga0 = A + (size_t)(m0 + (t >> 2)) * K_DIM + (t & 3) * 8;
    const bf16* ga1 = ga0 + (size_t)64 * K_DIM;
    const bf16* gb0 = W + (size_t)(n0 + (t >> 2)) * K_DIM + (t & 3) * 8;
    const bf16* gb1 = gb0 + (size_t)64 * K_DIM;
    bf16* la0 = As + t * 8;
    bf16* la1 = la0 + 2048;
    bf16* lb0 = Bs + t * 8;
    bf16* lb1 = lb0 + 2048;

    // Fragment read pointers: A-operand layout A[m=lane&15][k=quad*8+j]; B-op mirrored (gemm_bt).
    const bf16* pa = As + (wm + lr) * 32 + lq * 8;
    const bf16* pb = Bs + (wn + lr) * 32 + lq * 8;

    for (int kb = 0; kb < K_DIM; kb += 32) {
        gll16(ga0 + kb, la0);
        gll16(ga1 + kb, la1);
        gll16(gb0 + kb, lb0);
        gll16(gb1 + kb, lb1);
        __syncthreads();

        bf16x8 af[4], bfr[4];
#pragma unroll
        for (int i = 0; i < 4; ++i) af[i] = *(const bf16x8*)(pa + i * 16 * 32);
#pragma unroll
        for (int i = 0; i < 4; ++i) bfr[i] = *(const bf16x8*)(pb + i * 16 * 32);
#pragma unroll
        for (int mi = 0; mi < 4; ++mi)
#pragma unroll
            for (int ni = 0; ni < 4; ++ni)
                acc[mi][ni] = __builtin_amdgcn_mfma_f32_16x16x32_bf16(
                    af[mi], bfr[ni], acc[mi][ni], 0, 0, 0);
        __syncthreads();
    }

    // Epilogue: C/D layout col(n)=lane&15, row(m)=(lane>>4)*4+reg  [m89/m91-verified]
    float* Cb = C + (size_t)(m0 + wm) * N_DIM + n0 + wn;
#pragma unroll
    for (int mi = 0; mi < 4; ++mi)
#pragma unroll
        for (int ni = 0; ni < 4; ++ni)
#pragma unroll
            for (int r = 0; r < 4; ++r)
                Cb[(size_t)(mi * 16 + lq * 4 + r) * N_DIM + ni * 16 + lr] = acc[mi][ni][r];
}

extern "C" void kernel_launch(void* const* d_in, const int* in_sizes, int n_in,
                              void* d_out, int out_size, void* d_ws, size_t ws_size,
                              hipStream_t stream) {
    const float* x      = (const float*)d_in[0];  // (4,2048,4096) fp32
    const float* sw     = (const float*)d_in[1];  // (4096,4096) fp32, values +/-1
    const float* scales = (const float*)d_in[2];  // (131072,) fp32
    float* out = (float*)d_out;                   // (4,2048,4096) fp32

    // Workspace layout: [A bf16: M*K*2 = 64 MB][W bf16: N*K*2 = 32 MB]  (needs 96 MB)
    bf16* Abf = (bf16*)d_ws;
    bf16* Wbf = (bf16*)((char*)d_ws + (size_t)M_DIM * K_DIM * 2);

    cvt_x_kernel<<<(M_DIM * (size_t)K_DIM) / 8 / 256, 256, 0, stream>>>(x, (unsigned short*)Abf);
    wprep_kernel<<<(N_DIM * (size_t)K_DIM) / 8 / 256, 256, 0, stream>>>(sw, scales, (unsigned short*)Wbf);

    dim3 grid(N_DIM / 128, M_DIM / 128);  // (32, 64) = 2048 blocks
    gemm_bt_kernel<<<grid, 256, 0, stream>>>(Abf, Wbf, out);
}

// Round 2
// 539.679 us; speedup vs baseline: 1.2177x; 1.2177x over previous
//
#include <hip/hip_runtime.h>

// Problem constants: B=4, S=2048 -> M=8192 rows; OUT_F=N=4096; IN_F=K=4096; GROUP=128.
#define K_DIM 4096
#define N_DIM 4096
#define M_DIM 8192

typedef __bf16 bf16;
typedef __attribute__((ext_vector_type(8))) __bf16 bf16x8;
typedef __attribute__((ext_vector_type(4))) float f32x4;
typedef __attribute__((ext_vector_type(8))) unsigned short u16x8;

// fp32 -> bf16 round-to-nearest-even
__device__ inline unsigned short f2bf(float f) {
    unsigned u = __builtin_bit_cast(unsigned, f);
    u += 0x7fffu + ((u >> 16) & 1u);
    return (unsigned short)(u >> 16);
}

// ---- prep 1: x fp32 -> bf16 (8 elems/thread) ----
__global__ __launch_bounds__(256) void cvt_x_kernel(const float* __restrict__ x,
                                                    unsigned short* __restrict__ o) {
    const size_t i = (size_t)blockIdx.x * 256 + threadIdx.x;
    const float4* p = (const float4*)x + i * 2;
    float4 a = p[0], b = p[1];
    u16x8 v;
    v[0] = f2bf(a.x); v[1] = f2bf(a.y); v[2] = f2bf(a.z); v[3] = f2bf(a.w);
    v[4] = f2bf(b.x); v[5] = f2bf(b.y); v[6] = f2bf(b.z); v[7] = f2bf(b.w);
    *((u16x8*)o + i) = v;
}

// ---- prep 2: W[n,k] = bf16(sign_w[n,k] * scales[(n*K+k)/128]) ----
__global__ __launch_bounds__(256) void wprep_kernel(const float* __restrict__ sw,
                                                    const float* __restrict__ scales,
                                                    unsigned short* __restrict__ o) {
    const size_t i = (size_t)blockIdx.x * 256 + threadIdx.x;
    const float s = scales[i >> 4];
    const float4* p = (const float4*)sw + i * 2;
    float4 a = p[0], b = p[1];
    u16x8 v;
    v[0] = f2bf(a.x * s); v[1] = f2bf(a.y * s); v[2] = f2bf(a.z * s); v[3] = f2bf(a.w * s);
    v[4] = f2bf(b.x * s); v[5] = f2bf(b.y * s); v[6] = f2bf(b.z * s); v[7] = f2bf(b.w * s);
    *((u16x8*)o + i) = v;
}

__device__ inline void gll16(const bf16* g, bf16* l) {
    __builtin_amdgcn_global_load_lds(
        (const __attribute__((address_space(1))) void*)g,
        (__attribute__((address_space(3))) void*)l, 16, 0, 0);
}

// ---- GEMM: C[m,n] = sum_k A[m,k]*W[n,k]; BK=64, XOR-swizzled LDS cols ----
// 128x128 tile, 256 thr = 2x2 waves, each wave 4x4 of 16x16x32 MFMA, 32 MFMA/barrier.
// LDS layout: row-major [row][64], 16B segment (row, cstored) holds global
// col-block (cstored ^ (row&7)) -> row stride 128B bank aliasing broken, reads
// sit at the inherent 8-phase b128 floor.
__global__ __launch_bounds__(256) void gemm_bt_kernel(const bf16* __restrict__ A,
                                                      const bf16* __restrict__ W,
                                                      float* __restrict__ C) {
    __shared__ bf16 As[128 * 64];  // 16 KB
    __shared__ bf16 Bs[128 * 64];  // 16 KB

    const int t = threadIdx.x;
    const int m0 = blockIdx.y * 128;
    const int n0 = blockIdx.x * 128;
    const int lane = t & 63;
    const int w = t >> 6;
    const int wm = (w >> 1) * 64;
    const int wn = (w & 1) * 64;
    const int lr = lane & 15;
    const int lq = lane >> 4;

    f32x4 acc[4][4] = {};

    // Staging: seg = t + 256*j (j=0..3) per matrix. row = seg>>3 = (t>>3)+32j,
    // cstored = t&7 (const over j), global colblk = cstored ^ (row&7) = (t&7)^((t>>3)&7).
    const int srow = t >> 3;
    const int scol = (t & 7) ^ (srow & 7);
    const bf16* ga = A + (size_t)(m0 + srow) * K_DIM + scol * 8;
    const bf16* gb = W + (size_t)(n0 + srow) * K_DIM + scol * 8;
    bf16* la = As + t * 8;
    bf16* lb = Bs + t * 8;

    // Fragment pointers. Wanted global colblk for ks=0 is lq, for ks=1 is 4|lq.
    // Stored col = wanted ^ (row&7); row&7 == lr&7 for all mi (wm, mi*16 mult of 8).
    const int c0 = lq ^ (lr & 7);
    const bf16* pa0 = As + (wm + lr) * 64 + c0 * 8;
    const bf16* pb0 = Bs + (wn + lr) * 64 + c0 * 8;
    const bf16* pa1 = As + (wm + lr) * 64 + (c0 ^ 4) * 8;
    const bf16* pb1 = Bs + (wn + lr) * 64 + (c0 ^ 4) * 8;

    for (int kb = 0; kb < K_DIM; kb += 64) {
#pragma unroll
        for (int j = 0; j < 4; ++j)
            gll16(ga + kb + (size_t)(32 * j) * K_DIM, la + j * 2048);
#pragma unroll
        for (int j = 0; j < 4; ++j)
            gll16(gb + kb + (size_t)(32 * j) * K_DIM, lb + j * 2048);
        __syncthreads();

        bf16x8 af[4], bfr[4];
        // ks = 0 (global k 0..31 of this 64-block)
#pragma unroll
        for (int i = 0; i < 4; ++i) af[i] = *(const bf16x8*)(pa0 + i * 16 * 64);
#pragma unroll
        for (int i = 0; i < 4; ++i) bfr[i] = *(const bf16x8*)(pb0 + i * 16 * 64);
#pragma unroll
        for (int mi = 0; mi < 4; ++mi)
#pragma unroll
            for (int ni = 0; ni < 4; ++ni)
                acc[mi][ni] = __builtin_amdgcn_mfma_f32_16x16x32_bf16(
                    af[mi], bfr[ni], acc[mi][ni], 0, 0, 0);
        // ks = 1 (global k 32..63)
#pragma unroll
        for (int i = 0; i < 4; ++i) af[i] = *(const bf16x8*)(pa1 + i * 16 * 64);
#pragma unroll
        for (int i = 0; i < 4; ++i) bfr[i] = *(const bf16x8*)(pb1 + i * 16 * 64);
#pragma unroll
        for (int mi = 0; mi < 4; ++mi)
#pragma unroll
            for (int ni = 0; ni < 4; ++ni)
                acc[mi][ni] = __builtin_amdgcn_mfma_f32_16x16x32_bf16(
                    af[mi], bfr[ni], acc[mi][ni], 0, 0, 0);
        __syncthreads();
    }

    // Epilogue: C/D layout col(n)=lane&15, row(m)=(lane>>4)*4+reg [m89/m91-verified]
    float* Cb = C + (size_t)(m0 + wm) * N_DIM + n0 + wn;
#pragma unroll
    for (int mi = 0; mi < 4; ++mi)
#pragma unroll
        for (int ni = 0; ni < 4; ++ni)
#pragma unroll
            for (int r = 0; r < 4; ++r)
                Cb[(size_t)(mi * 16 + lq * 4 + r) * N_DIM + ni * 16 + lr] = acc[mi][ni][r];
}

extern "C" void kernel_launch(void* const* d_in, const int* in_sizes, int n_in,
                              void* d_out, int out_size, void* d_ws, size_t ws_size,
                              hipStream_t stream) {
    const float* x      = (const float*)d_in[0];
    const float* sw     = (const float*)d_in[1];
    const float* scales = (const float*)d_in[2];
    float* out = (float*)d_out;

    bf16* Abf = (bf16*)d_ws;                                   // 64 MB
    bf16* Wbf = (bf16*)((char*)d_ws + (size_t)M_DIM * K_DIM * 2);  // +32 MB

    cvt_x_kernel<<<(M_DIM * (size_t)K_DIM) / 8 / 256, 256, 0, stream>>>(x, (unsigned short*)Abf);
    wprep_kernel<<<(N_DIM * (size_t)K_DIM) / 8 / 256, 256, 0, stream>>>(sw, scales, (unsigned short*)Wbf);

    dim3 grid(N_DIM / 128, M_DIM / 128);  // (32, 64)
    gemm_bt_kernel<<<grid, 256, 0, stream>>>(Abf, Wbf, out);
}

// Round 3
// 517.787 us; speedup vs baseline: 1.2691x; 1.0423x over previous
//
#include <hip/hip_runtime.h>

// Problem constants: B=4, S=2048 -> M=8192 rows; OUT_F=N=4096; IN_F=K=4096; GROUP=128.
#define K_DIM 4096
#define N_DIM 4096
#define M_DIM 8192

typedef __bf16 bf16;
typedef __attribute__((ext_vector_type(8))) __bf16 bf16x8;
typedef __attribute__((ext_vector_type(16))) float f32x16;
typedef __attribute__((ext_vector_type(8))) unsigned short u16x8;

// fp32 -> bf16 round-to-nearest-even
__device__ inline unsigned short f2bf(float f) {
    unsigned u = __builtin_bit_cast(unsigned, f);
    u += 0x7fffu + ((u >> 16) & 1u);
    return (unsigned short)(u >> 16);
}

// ---- fused prep: blocks [0,16384) convert x; blocks [16384,24576) build W ----
// W[n,k] = bf16(sign_w[n,k] * scales[(n*K+k)/128]); thread's 8 elems share one group.
__global__ __launch_bounds__(256) void prep_kernel(const float* __restrict__ x,
                                                   const float* __restrict__ sw,
                                                   const float* __restrict__ scales,
                                                   unsigned short* __restrict__ oA,
                                                   unsigned short* __restrict__ oW) {
    const int b = blockIdx.x;
    if (b < 16384) {
        const size_t i = (size_t)b * 256 + threadIdx.x;
        const float4* p = (const float4*)x + i * 2;
        float4 a = p[0], c = p[1];
        u16x8 v;
        v[0] = f2bf(a.x); v[1] = f2bf(a.y); v[2] = f2bf(a.z); v[3] = f2bf(a.w);
        v[4] = f2bf(c.x); v[5] = f2bf(c.y); v[6] = f2bf(c.z); v[7] = f2bf(c.w);
        *((u16x8*)oA + i) = v;
    } else {
        const size_t i = (size_t)(b - 16384) * 256 + threadIdx.x;
        const float s = scales[i >> 4];
        const float4* p = (const float4*)sw + i * 2;
        float4 a = p[0], c = p[1];
        u16x8 v;
        v[0] = f2bf(a.x * s); v[1] = f2bf(a.y * s); v[2] = f2bf(a.z * s); v[3] = f2bf(a.w * s);
        v[4] = f2bf(c.x * s); v[5] = f2bf(c.y * s); v[6] = f2bf(c.z * s); v[7] = f2bf(c.w * s);
        *((u16x8*)oW + i) = v;
    }
}

__device__ inline void gll16(const bf16* g, bf16* l) {
    __builtin_amdgcn_global_load_lds(
        (const __attribute__((address_space(1))) void*)g,
        (__attribute__((address_space(3))) void*)l, 16, 0, 0);
}

// ---- GEMM: C[m,n] = sum_k A[m,k]*W[n,k] ----
// Block tile 256x128, BK=64. 4 waves in 2x2; wave tile 128x64 = 4x2 frags of
// mfma_f32_32x32x16_bf16. 42.7 FLOP per LDS byte (vs 32 for 64x64 wave tile).
// LDS: row-major [row][64] bf16, XOR-swizzled 16B col-blocks:
// stored_cb = global_cb ^ (row&7) -> frag reads conflict-free (8-phase floor).
__global__ __launch_bounds__(256, 2) void gemm_bt_kernel(const bf16* __restrict__ A,
                                                         const bf16* __restrict__ W,
                                                         float* __restrict__ C) {
    __shared__ bf16 As[256 * 64];  // 32 KB
    __shared__ bf16 Bs[128 * 64];  // 16 KB

    const int t = threadIdx.x;
    const int m0 = blockIdx.y * 256;
    const int n0 = blockIdx.x * 128;
    const int lane = t & 63;
    const int w = t >> 6;
    const int wm = (w >> 1) * 128;  // wave m-offset in block tile
    const int wn = (w & 1) * 64;    // wave n-offset
    const int ln = lane & 31;       // row within 32x32 frag
    const int hl = lane >> 5;       // half: selects k 8-block

    f32x16 acc[4][2] = {};  // [mi][ni], 128 VGPRs

    // Staging. A: 2048 16B segs (8/thread), B: 1024 (4/thread).
    // seg s -> row s>>3, stored col t&7; global colblk = (t&7)^(row&7);
    // row&7 = (t>>3)&7 for all j (j steps rows by 32).
    const int srow = t >> 3;
    const int scol = (t & 7) ^ (srow & 7);
    const bf16* ga = A + (size_t)(m0 + srow) * K_DIM + scol * 8;
    const bf16* gb = W + (size_t)(n0 + srow) * K_DIM + scol * 8;
    bf16* la = As + t * 8;
    bf16* lb = Bs + t * 8;

    // Fragment addressing: row = (wm|wn) + {mi,ni}*32 + ln (all offsets mult of 8
    // -> row&7 == ln&7). Wanted global cb for kstep ks is ks*2+hl; stored cb =
    // (ks*2+hl) ^ (ln&7). Precompute the 4 column byte-offsets.
    int co[4];
#pragma unroll
    for (int ks = 0; ks < 4; ++ks) co[ks] = ((ks * 2 + hl) ^ (ln & 7)) * 8;
    const bf16* paRow = As + (wm + ln) * 64;
    const bf16* pbRow = Bs + (wn + ln) * 64;

    for (int kb = 0; kb < K_DIM; kb += 64) {
#pragma unroll
        for (int j = 0; j < 8; ++j)
            gll16(ga + kb + (size_t)(32 * j) * K_DIM, la + j * 2048);
#pragma unroll
        for (int j = 0; j < 4; ++j)
            gll16(gb + kb + (size_t)(32 * j) * K_DIM, lb + j * 2048);
        __syncthreads();

#pragma unroll
        for (int ks = 0; ks < 4; ++ks) {
            bf16x8 af[4], bfr[2];
#pragma unroll
            for (int mi = 0; mi < 4; ++mi)
                af[mi] = *(const bf16x8*)(paRow + mi * 2048 + co[ks]);
#pragma unroll
            for (int ni = 0; ni < 2; ++ni)
                bfr[ni] = *(const bf16x8*)(pbRow + ni * 2048 + co[ks]);
#pragma unroll
            for (int mi = 0; mi < 4; ++mi)
#pragma unroll
                for (int ni = 0; ni < 2; ++ni)
                    acc[mi][ni] = __builtin_amdgcn_mfma_f32_32x32x16_bf16(
                        af[mi], bfr[ni], acc[mi][ni], 0, 0, 0);
        }
        __syncthreads();
    }

    // Epilogue: 32x32 C/D layout col=lane&31, row=(reg&3)+8*(reg>>2)+4*(lane>>5)
    // [m74/m101-verified]
    float* Cb = C + (size_t)(m0 + wm) * N_DIM + n0 + wn;
#pragma unroll
    for (int mi = 0; mi < 4; ++mi)
#pragma unroll
        for (int ni = 0; ni < 2; ++ni)
#pragma unroll
            for (int r = 0; r < 16; ++r) {
                const int row = mi * 32 + (r & 3) + 8 * (r >> 2) + 4 * hl;
                Cb[(size_t)row * N_DIM + ni * 32 + ln] = acc[mi][ni][r];
            }
}

extern "C" void kernel_launch(void* const* d_in, const int* in_sizes, int n_in,
                              void* d_out, int out_size, void* d_ws, size_t ws_size,
                              hipStream_t stream) {
    const float* x      = (const float*)d_in[0];
    const float* sw     = (const float*)d_in[1];
    const float* scales = (const float*)d_in[2];
    float* out = (float*)d_out;

    bf16* Abf = (bf16*)d_ws;                                       // 64 MB
    bf16* Wbf = (bf16*)((char*)d_ws + (size_t)M_DIM * K_DIM * 2);  // +32 MB

    prep_kernel<<<24576, 256, 0, stream>>>(x, sw, scales,
                                           (unsigned short*)Abf, (unsigned short*)Wbf);

    dim3 grid(N_DIM / 128, M_DIM / 256);  // (32, 32) = 1024 blocks
    gemm_bt_kernel<<<grid, 256, 0, stream>>>(Abf, Wbf, out);
}